// Round 8
// baseline (256.433 us; speedup 1.0000x reference)
//
#include <hip/hip_runtime.h>
#include <math.h>

#define B 4096
#define D 512
#define TOPK 32

constexpr float OT_EPS_F = 0.05f;
constexpr float FLOORK   = 1e-12f;
constexpr float AMASS    = 1.0f / 4096.0f;   // exact 2^-12
constexpr float TAU      = 1.8f;             // candidate prefilter threshold on z

__device__ __forceinline__ float softplusf(float x) {
    return fmaxf(x, 0.0f) + log1pf(expf(-fabsf(x)));
}
// monotone float<->uint key: order-preserving for all finite floats
__device__ __forceinline__ unsigned int fkey(float f) {
    unsigned int x = __float_as_uint(f);
    return x ^ ((x & 0x80000000u) ? 0xFFFFFFFFu : 0x80000000u);
}
__device__ __forceinline__ float finv(unsigned int k) {
    unsigned int x = (k & 0x80000000u) ? (k ^ 0x80000000u) : ~k;
    return __uint_as_float(x);
}
__device__ __forceinline__ float rcpf_(float x) { return __builtin_amdgcn_rcpf(x); }

// Native LDS float atomic add (ds_add_f32).
__device__ __forceinline__ void lds_add_f32(float* p, float v) {
    unsigned int off = (unsigned int)(reinterpret_cast<uintptr_t>(p));
    asm volatile("ds_add_f32 %0, %1" :: "v"(off), "v"(v) : "memory");
}
// Single-wave LDS fence: drain DS ops, pin scheduler (rule #18).
__device__ __forceinline__ void lgkm0() {
    asm volatile("s_waitcnt lgkmcnt(0)" ::: "memory");
    __builtin_amdgcn_sched_barrier(0);
}

// ---------------------------------------------------------------------------
// k1: wave-per-row (4 rows / 256-block). Stream row with float4 loads,
// softplus partial + row max (registers), prefilter candidates z > TAU into
// a per-wave LDS list, then EXACT top-32 via ballot-based 32-bit binary
// search. Pathologies -> flags[row] -> exact fallback kernel.
// Fused: one ratio sample per row. Writes per-row sum/max partials.
// ---------------------------------------------------------------------------
__global__ __launch_bounds__(256) void k1_row(const float* __restrict__ logits,
                                              const float* __restrict__ text,
                                              const float* __restrict__ image,
                                              const float* __restrict__ bias_p,
                                              float* __restrict__ rowsum,
                                              unsigned int* __restrict__ rowmaxk,
                                              int* __restrict__ top_idx,
                                              float* __restrict__ top_z,
                                              float* __restrict__ ratio,
                                              unsigned int* __restrict__ flags) {
    __shared__ unsigned int candk[4][128];
    __shared__ unsigned int candi[4][128];
    __shared__ unsigned int wcnt[4];

    const int tid = threadIdx.x, w = tid >> 6, lane = tid & 63;
    const int row = (blockIdx.x << 2) + w;
    const float bias = bias_p[0];
    const float* lr = logits + (size_t)row * B;
    const float4* lr4 = (const float4*)lr;

    if (lane == 0) wcnt[w] = 0;
    candk[w][lane] = 0; candk[w][lane + 64] = 0;

    float lsum = 0.0f, lmax = -INFINITY;
    bool ovf = false;

#define K1ELEM(ZV, CC) do {                                                   \
        float z_ = (ZV) + bias;                                               \
        bool dg_ = ((CC) == row);                                             \
        lsum += dg_ ? softplusf(-z_) : softplusf(z_);                         \
        float zm_ = dg_ ? -INFINITY : z_;                                     \
        lmax = fmaxf(lmax, zm_);                                              \
        if (zm_ > TAU) {                                                      \
            unsigned int p_ = atomicAdd(&wcnt[w], 1u);                        \
            if (p_ < 128u) { candk[w][p_] = fkey(zm_);                        \
                             candi[w][p_] = (unsigned int)(CC); }             \
            else ovf = true;                                                  \
        } } while (0)

    #pragma unroll
    for (int t = 0; t < 16; ++t) {
        float4 z4 = lr4[lane + (t << 6)];
        int cb = (lane << 2) + (t << 8);
        K1ELEM(z4.x, cb);
        K1ELEM(z4.y, cb + 1);
        K1ELEM(z4.z, cb + 2);
        K1ELEM(z4.w, cb + 3);
    }
#undef K1ELEM
    __syncthreads();

    for (int o = 1; o < 64; o <<= 1) {
        lsum += __shfl_xor(lsum, o);
        lmax = fmaxf(lmax, __shfl_xor(lmax, o));
    }
    if (lane == 0) { rowsum[row] = lsum; rowmaxk[row] = fkey(lmax); }

    const unsigned int n = wcnt[w];
    bool fb = (n < (unsigned)TOPK) || (n > 128u) || (__ballot(ovf) != 0ull);

    const unsigned int c0k = candk[w][lane], c1k = candk[w][lane + 64];
    const unsigned int i0  = candi[w][lane], i1  = candi[w][lane + 64];

    if (!fb) {
        unsigned int K = 0u;
        for (int b = 31; b >= 0; --b) {
            unsigned int tr = K | (1u << b);
            int cnt = __popcll(__ballot(c0k >= tr)) + __popcll(__ballot(c1k >= tr));
            if (cnt >= TOPK) K = tr;
        }
        unsigned long long m0g = __ballot(c0k > K), m1g = __ballot(c1k > K);
        unsigned long long m0e = __ballot(c0k == K), m1e = __ballot(c1k == K);
        int cnt_gt = __popcll(m0g) + __popcll(m1g);
        int kneed  = TOPK - cnt_gt;
        int eqc    = __popcll(m0e) + __popcll(m1e);
        if (eqc != kneed) {
            fb = true;
        } else {
            unsigned long long lmlt = (1ull << lane) - 1ull;
            size_t rb = (size_t)row * TOPK;
            int r0 = __popcll(m0g & lmlt);
            if (c0k > K) { top_idx[rb + r0] = (int)i0; top_z[rb + r0] = finv(c0k); }
            int r1 = __popcll(m0g) + __popcll(m1g & lmlt);
            if (c1k > K) { top_idx[rb + r1] = (int)i1; top_z[rb + r1] = finv(c1k); }
            int e0 = cnt_gt + __popcll(m0e & lmlt);
            if (c0k == K) { top_idx[rb + e0] = (int)i0; top_z[rb + e0] = finv(c0k); }
            int e1 = cnt_gt + __popcll(m0e) + __popcll(m1e & lmlt);
            if (c1k == K) { top_idx[rb + e1] = (int)i1; top_z[rb + e1] = finv(c1k); }
        }
    }
    if (fb && lane == 0) flags[row] = 1u;

    // ---- fused ratio sample ----
    unsigned int hh = (unsigned int)row * 2654435761u;
    int j = (int)(((unsigned int)row + 1u + (hh % 4095u)) & 4095u);   // j != row
    const float4* tr4 = (const float4*)(text + (size_t)row * D);
    const float4* ir4 = (const float4*)(image + (size_t)j * D);
    float4 a0 = tr4[lane], b0 = ir4[lane];
    float4 a1 = tr4[lane + 64], b1 = ir4[lane + 64];
    float s3 = a0.x * b0.x + a0.y * b0.y + a0.z * b0.z + a0.w * b0.w
             + a1.x * b1.x + a1.y * b1.y + a1.z * b1.z + a1.w * b1.w;
    for (int o = 1; o < 64; o <<= 1) s3 += __shfl_xor(s3, o);
    if (lane == 0) ratio[row] = lr[j] / (s3 + 1e-8f);
}

// ---------------------------------------------------------------------------
// k1f: exact fallback for flagged rows (LDS radix select).
// ---------------------------------------------------------------------------
__global__ __launch_bounds__(256) void k1_fallback(const float* __restrict__ logits,
                                                   const float* __restrict__ bias_p,
                                                   const unsigned int* __restrict__ flags,
                                                   int* __restrict__ top_idx,
                                                   float* __restrict__ top_z) {
    const int row = blockIdx.x;
    if (flags[row] == 0u) return;

    __shared__ unsigned int skey[B];
    __shared__ unsigned int histm[4 * 257 + 4];
    __shared__ unsigned int selb, selk;
    __shared__ int cnt_gt, cnt_eq;
    __shared__ int eqi[64];

    const int tid = threadIdx.x, wid = tid >> 6, lane = tid & 63;
    const float bias = bias_p[0];
    const float* lr = logits + (size_t)row * B;

    #pragma unroll
    for (int t = 0; t < 16; ++t) {
        int c = tid + (t << 8);
        float z = lr[c] + bias;
        skey[c] = fkey((c == row) ? -INFINITY : z);
    }
    if (tid == 0) { cnt_gt = 0; cnt_eq = 0; }
    __syncthreads();

    unsigned int prefix = 0, kneed = TOPK;
    for (int r = 0; r < 4; ++r) {
        for (int i = tid; i < 4 * 257 + 4; i += 256) histm[i] = 0;
        __syncthreads();
        const int shift = 24 - 8 * r;
        #pragma unroll
        for (int t = 0; t < 16; ++t) {
            int c = tid + (t << 8);
            unsigned int kx = skey[c];
            bool part = (r == 0) || ((kx >> (32 - 8 * r)) == prefix);
            if (part) atomicAdd(&histm[wid * 257 + ((kx >> shift) & 255u)], 1u);
        }
        __syncthreads();
        unsigned int h = histm[tid] + histm[257 + tid] + histm[514 + tid] + histm[771 + tid];
        unsigned int s = h;
        for (int off = 1; off < 64; off <<= 1) {
            unsigned int o = __shfl_down(s, off);
            if (lane + off < 64) s += o;
        }
        if (lane == 0) histm[1028 + wid] = s;
        __syncthreads();
        unsigned int coarse = 0;
        for (int ww = wid + 1; ww < 4; ++ww) coarse += histm[1028 + ww];
        unsigned int incl = s + coarse, strict = incl - h;
        if (strict < kneed && kneed <= incl) { selb = (unsigned int)tid; selk = kneed - strict; }
        __syncthreads();
        prefix = (prefix << 8) | selb;
        kneed = selk;
        __syncthreads();
    }
    const unsigned int K32 = prefix;

    #pragma unroll
    for (int t = 0; t < 16; ++t) {
        int c = tid + (t << 8);
        unsigned int kx = skey[c];
        if (kx > K32) {
            int p = atomicAdd(&cnt_gt, 1);
            top_idx[(size_t)row * TOPK + p] = c;
            top_z [(size_t)row * TOPK + p] = finv(kx);
        } else if (kx == K32) {
            int p = atomicAdd(&cnt_eq, 1);
            if (p < 64) eqi[p] = c;
        }
    }
    __syncthreads();
    if (tid == 0) {
        int q = (int)kneed, base = cnt_gt, E = cnt_eq;
        float zv = finv(K32);
        if (E <= 64) {
            for (int s2 = 0; s2 < q; ++s2) {
                int best = 0x7FFFFFFF, bp = 0;
                for (int e = 0; e < E; ++e) { int ix = eqi[e]; if (ix < best) { best = ix; bp = e; } }
                eqi[bp] = 0x7FFFFFFF;
                top_idx[(size_t)row * TOPK + base + s2] = best;
                top_z [(size_t)row * TOPK + base + s2] = zv;
            }
        } else {
            int taken = 0;
            for (int c = 0; c < B && taken < q; ++c)
                if (skey[c] == K32) {
                    top_idx[(size_t)row * TOPK + base + taken] = c;
                    top_z [(size_t)row * TOPK + base + taken] = zv;
                    ++taken;
                }
        }
    }
}

// ---------------------------------------------------------------------------
// k2: reduce per-row partials -> global Mkey + base-loss f64 sum.
// ---------------------------------------------------------------------------
__global__ __launch_bounds__(256) void k2_reduce(const float* __restrict__ rowsum,
                                                 const unsigned int* __restrict__ rowmaxk,
                                                 unsigned int* __restrict__ Mkey,
                                                 double* __restrict__ base_acc) {
    __shared__ double sd[4];
    __shared__ unsigned int sm[4];
    const int tid = threadIdx.x, wid = tid >> 6, lane = tid & 63;
    double s = 0.0; unsigned int mk = 0u;
    for (int i = tid; i < B; i += 256) {
        s += (double)rowsum[i];
        unsigned int k = rowmaxk[i];
        mk = (k > mk) ? k : mk;
    }
    for (int o = 1; o < 64; o <<= 1) {
        s += __shfl_xor(s, o);
        unsigned int om = __shfl_xor(mk, o);
        mk = (om > mk) ? om : mk;
    }
    if (lane == 0) { sd[wid] = s; sm[wid] = mk; }
    __syncthreads();
    if (tid == 0) {
        *base_acc = sd[0] + sd[1] + sd[2] + sd[3];
        *Mkey = max(max(sm[0], sm[1]), max(sm[2], sm[3]));
    }
}

// ---------------------------------------------------------------------------
// k3: sparse correction list (K - 1e-12) over surviving top-k entries.
// ---------------------------------------------------------------------------
__global__ __launch_bounds__(256) void k3_build(const float* __restrict__ top_z,
                                                const int* __restrict__ top_idx,
                                                const unsigned int* __restrict__ Mkey,
                                                unsigned int* __restrict__ mcount,
                                                unsigned int* __restrict__ lij,
                                                float* __restrict__ lval) {
    const int gid = blockIdx.x * 256 + threadIdx.x;
    const float M = finv(Mkey[0]);
    const float z = top_z[gid];
    const float c = fmaxf(M - z, 0.0f);
    const float e = expf(-(c / OT_EPS_F));
    if (e > FLOORK) {
        unsigned int pos = atomicAdd(mcount, 1u);
        unsigned int i = (unsigned int)(gid >> 5);
        unsigned int j = (unsigned int)top_idx[gid];
        lij[pos] = (i << 12) | j;
        lval[pos] = e - FLOORK;
    }
}

// ---------------------------------------------------------------------------
// k4: 1 block x 128 threads. Wave 0 = single-wave branchless Sinkhorn with
// NO barriers (raw lgkmcnt(0) fences — valid single-wave). Wave 1 = same-CU
// keepalive: spins on an LDS flag doing FMAs + ds_reads, keeping this CU's
// SIMD/LDS clock domains awake (test of the per-CU sleep/wake theory).
// ---------------------------------------------------------------------------
#define LDSP (B + 16)

template<int NS>
__device__ void sink_fast(int m, const unsigned int* __restrict__ lij,
                          const float* __restrict__ lval,
                          float* __restrict__ vout,
                          float* accr, float* accv,
                          unsigned int* rown, unsigned int* coln) {
    const int lane = threadIdx.x & 63;
    for (int i = lane; i < LDSP; i += 64) { accr[i] = 0.0f; accv[i] = 0.0f; }
    for (int i = lane; i < B; i += 64) { coln[i] = 0xFFFFFFFFu; rown[i] = 0xFFFFFFFFu; }
    lgkm0();

    unsigned int er[NS], ec[NS];
    float ev[NS], vv[NS], uu[NS], fRf[NS], fCf[NS];
    #pragma unroll
    for (int t = 0; t < NS; ++t) {
        int e = lane + (t << 6);
        bool vld = (e < m);
        unsigned int ij = vld ? lij[e] : 0u;
        er[t] = vld ? (ij >> 12) : (unsigned int)B;
        ec[t] = vld ? (ij & 4095u) : (unsigned int)B;
        ev[t] = vld ? lval[e] : 0.0f;
        vv[t] = 1.0f; uu[t] = 1.0f;
        if (vld) {
            atomicMin(&rown[er[t]], (unsigned int)e);
            atomicMin(&coln[ec[t]], (unsigned int)e);
        }
    }
    lgkm0();
    float nrf = 0.0f, ncf = 0.0f;
    #pragma unroll
    for (int t = 0; t < NS; ++t) {
        unsigned int e = (unsigned int)(lane + (t << 6));
        bool vld = ((int)e < m);
        bool fr = vld && (rown[er[t]] == e);
        bool fc = vld && (coln[ec[t]] == e);
        fRf[t] = fr ? 1.0f : 0.0f;
        fCf[t] = fc ? 1.0f : 0.0f;
        nrf += fRf[t]; ncf += fCf[t];
    }
    for (int o = 1; o < 64; o <<= 1) { nrf += __shfl_xor(nrf, o); ncf += __shfl_xor(ncf, o); }
    const float bgr = (float)B - nrf, bgc = (float)B - ncf;
    float u0 = 1.0f, v0 = 1.0f;
    const int ss = B + 8 + (lane & 7);
    const float4* sr4 = (const float4*)&accr[B + 8];
    const float4* sv4 = (const float4*)&accv[B + 8];

    for (int it = 0; it < 30; ++it) {
        // ---- u phase ----
        #pragma unroll
        for (int t = 0; t < NS; ++t) lds_add_f32(&accr[er[t]], ev[t] * vv[t]);
        float svc = 0.0f;
        #pragma unroll
        for (int t = 0; t < NS; ++t) svc += fCf[t] * vv[t];
        lds_add_f32(&accr[ss], svc);
        lgkm0();
        float4 sa = sr4[0], sb = sr4[1];
        float ar[NS];
        #pragma unroll
        for (int t = 0; t < NS; ++t) ar[t] = accr[er[t]];
        const float Sv = bgc * v0 + (sa.x + sa.y + sa.z + sa.w + sb.x + sb.y + sb.z + sb.w);
        const float bgu = FLOORK * Sv + 1e-8f;
        u0 = AMASS * rcpf_(bgu);
        #pragma unroll
        for (int t = 0; t < NS; ++t) uu[t] = AMASS * rcpf_(bgu + ar[t]);
        #pragma unroll
        for (int t = 0; t < NS; ++t) accr[er[t]] = 0.0f;   // in-order DS: reads above precede
        accr[ss] = 0.0f;

        // ---- v phase ----
        #pragma unroll
        for (int t = 0; t < NS; ++t) lds_add_f32(&accv[ec[t]], ev[t] * uu[t]);
        float usc = 0.0f;
        #pragma unroll
        for (int t = 0; t < NS; ++t) usc += fRf[t] * uu[t];
        lds_add_f32(&accv[ss], usc);
        lgkm0();
        float4 ta = sv4[0], tb = sv4[1];
        float ac[NS];
        #pragma unroll
        for (int t = 0; t < NS; ++t) ac[t] = accv[ec[t]];
        const float Su = bgr * u0 + (ta.x + ta.y + ta.z + ta.w + tb.x + tb.y + tb.z + tb.w);
        const float bgv = FLOORK * Su + 1e-8f;
        v0 = AMASS * rcpf_(bgv);
        #pragma unroll
        for (int t = 0; t < NS; ++t) vv[t] = AMASS * rcpf_(bgv + ac[t]);
        #pragma unroll
        for (int t = 0; t < NS; ++t) accv[ec[t]] = 0.0f;
        accv[ss] = 0.0f;
    }
    lgkm0();
    #pragma unroll
    for (int t = 0; t < NS; ++t) {
        if (fCf[t] > 0.0f) accv[ec[t]] = vv[t];
    }
    lgkm0();
    for (int i = lane; i < B; i += 64) {
        vout[i] = (coln[i] != 0xFFFFFFFFu) ? accv[i] : v0;
    }
}

// Generic dense fallback (m > 1024): correct, slow, never triggers here.
// Single-wave (wave 0 only), lgkm0 fences.
__device__ void sink_generic(int m, const unsigned int* __restrict__ lij,
                             const float* __restrict__ lval,
                             float* __restrict__ vout,
                             float* vden, float* accr, float* accv) {
    const int lane = threadIdx.x & 63;
    for (int i = lane; i < B; i += 64) vden[i] = 1.0f;
    lgkm0();
    for (int it = 0; it < 30; ++it) {
        float s = 0.0f;
        for (int i = lane; i < B; i += 64) { s += vden[i]; accr[i] = 0.0f; }
        for (int o = 1; o < 64; o <<= 1) s += __shfl_xor(s, o);
        lgkm0();
        const float bgu = FLOORK * s + 1e-8f;
        for (int e = lane; e < m; e += 64) {
            unsigned int ij = lij[e];
            lds_add_f32(&accr[ij >> 12], lval[e] * vden[ij & 4095u]);
        }
        lgkm0();
        float su = 0.0f;
        for (int i = lane; i < B; i += 64) { su += AMASS / (bgu + accr[i]); accv[i] = 0.0f; }
        for (int o = 1; o < 64; o <<= 1) su += __shfl_xor(su, o);
        lgkm0();
        const float bgv = FLOORK * su + 1e-8f;
        for (int e = lane; e < m; e += 64) {
            unsigned int ij = lij[e];
            lds_add_f32(&accv[ij & 4095u], lval[e] * (AMASS / (bgu + accr[ij >> 12])));
        }
        lgkm0();
        for (int i = lane; i < B; i += 64) vden[i] = AMASS / (bgv + accv[i]);
        lgkm0();
    }
    for (int i = lane; i < B; i += 64) vout[i] = vden[i];
}

__global__ __launch_bounds__(128) void k4_sinkhorn(const unsigned int* __restrict__ mcount,
                                                   const unsigned int* __restrict__ lij,
                                                   const float* __restrict__ lval,
                                                   float* __restrict__ vout) {
    __shared__ __align__(16) float Lds[4 * LDSP];
    __shared__ volatile unsigned int lflag;

    const int wave = threadIdx.x >> 6;
    if (wave == 1) {
        if ((threadIdx.x & 63) == 0) lflag = 0u;
    }
    __syncthreads();   // the ONLY barrier: flag initialized, both waves present

    if (wave == 1) {
        // keepalive: keep this CU's SIMD + LDS pipes active while wave 0 runs
        float x0 = 1.0f + (float)threadIdx.x * 1e-6f, x1 = 1.1f, x2 = 1.2f, x3 = 1.3f;
        while (lflag == 0u) {
            #pragma unroll
            for (int i = 0; i < 16; ++i) {
                x0 = fmaf(x0, 1.0000001f, 1e-7f);
                x1 = fmaf(x1, 1.0000001f, 1e-7f);
                x2 = fmaf(x2, 1.0000001f, 1e-7f);
                x3 = fmaf(x3, 1.0000001f, 1e-7f);
            }
            asm volatile("" :: "v"(x0), "v"(x1), "v"(x2), "v"(x3));
        }
        return;
    }

    const int m = (int)mcount[0];
    float* accr = Lds;
    float* accv = Lds + LDSP;
    unsigned int* rown = (unsigned int*)(Lds + 2 * LDSP);
    unsigned int* coln = (unsigned int*)(Lds + 3 * LDSP);
    if (m <= 64 * 4)       sink_fast<4> (m, lij, lval, vout, accr, accv, rown, coln);
    else if (m <= 64 * 16) sink_fast<16>(m, lij, lval, vout, accr, accv, rown, coln);
    else                   sink_generic (m, lij, lval, vout, (float*)rown, accr, accv);
    lgkm0();
    if ((threadIdx.x & 63) == 0) lflag = 1u;   // release keepalive
}

// ---------------------------------------------------------------------------
// k5: per row: weights = K*v (u cancels after row-normalization; the final
// unit-normalization absorbs any uniform clamp-scale), synthetic negative,
// normalize, dot with text row.
// ---------------------------------------------------------------------------
__global__ __launch_bounds__(256) void k5_synth(const int* __restrict__ top_idx,
                                                const float* __restrict__ top_z,
                                                const unsigned int* __restrict__ Mkey,
                                                const float* __restrict__ v,
                                                const float* __restrict__ image,
                                                const float* __restrict__ text,
                                                float* __restrict__ synth_sim) {
    __shared__ float sw[TOPK];
    __shared__ int   sj[TOPK];
    __shared__ float red[4];
    __shared__ float bcast;

    const int row = blockIdx.x, tid = threadIdx.x;
    const int wid = tid >> 6, lane = tid & 63;
    const float M = finv(Mkey[0]);

    if (tid < 64) {
        float wt = 0.0f;
        if (tid < TOPK) {
            int j = top_idx[(size_t)row * TOPK + tid];
            float z = top_z[(size_t)row * TOPK + tid];
            float c = fmaxf(M - z, 0.0f);
            float K = fmaxf(expf(-(c / OT_EPS_F)), FLOORK);
            wt = K * v[j];
            sj[tid] = j;
            sw[tid] = wt;
        }
        float s = wt;
        for (int off = 32; off; off >>= 1) s += __shfl_down(s, off);
        if (tid == 0) bcast = fmaxf(s, 1e-8f);
    }
    __syncthreads();
    if (tid < TOPK) sw[tid] = sw[tid] / bcast;   // row_weights (up to uniform scale)
    __syncthreads();

    float s0 = 0.0f, s1 = 0.0f;
    for (int t = 0; t < TOPK; ++t) {
        float wv = sw[t];
        const float* img = image + (size_t)sj[t] * D;
        s0 += wv * img[tid];
        s1 += wv * img[tid + 256];
    }
    float nn = s0 * s0 + s1 * s1;
    for (int off = 32; off; off >>= 1) nn += __shfl_down(nn, off);
    if (lane == 0) red[wid] = nn;
    __syncthreads();
    float norm2 = red[0] + red[1] + red[2] + red[3];
    float den = sqrtf(norm2) + 1e-8f;
    float p = (s0 / den) * text[(size_t)row * D + tid] +
              (s1 / den) * text[(size_t)row * D + tid + 256];
    __syncthreads();
    for (int off = 32; off; off >>= 1) p += __shfl_down(p, off);
    if (lane == 0) red[wid] = p;
    __syncthreads();
    if (tid == 0) synth_sim[row] = red[0] + red[1] + red[2] + red[3];
}

// ---------------------------------------------------------------------------
// k78: median of ratio via radix select, then gate + final combine.
// ---------------------------------------------------------------------------
__global__ __launch_bounds__(256) void k78_final(const float* __restrict__ ratio,
                                                 const float* __restrict__ synth_sim,
                                                 const double* __restrict__ base_acc,
                                                 float* __restrict__ out) {
    __shared__ unsigned int skey[B];
    __shared__ unsigned int histm[4 * 257 + 4];
    __shared__ unsigned int selb, selk;
    __shared__ double rs[4];
    __shared__ float rg[4];

    const int tid = threadIdx.x, wid = tid >> 6, lane = tid & 63;

    #pragma unroll
    for (int t = 0; t < 16; ++t) {
        int c = tid + (t << 8);
        skey[c] = fkey(ratio[c]);
    }
    __syncthreads();

    unsigned int prefix = 0, kneed = 2048;
    for (int r = 0; r < 4; ++r) {
        for (int i = tid; i < 4 * 257 + 4; i += 256) histm[i] = 0;
        __syncthreads();
        const int shift = 24 - 8 * r;
        unsigned int cb = 0xFFFFFFFFu, cc = 0;
        #pragma unroll
        for (int t = 0; t < 16; ++t) {
            unsigned int kx = skey[tid + (t << 8)];
            bool part = (r == 0) || ((kx >> (32 - 8 * r)) == prefix);
            if (part) {
                unsigned int bin = (kx >> shift) & 255u;
                if (bin == cb) ++cc;
                else {
                    if (cc) atomicAdd(&histm[wid * 257 + cb], cc);
                    cb = bin; cc = 1;
                }
            }
        }
        if (cc) atomicAdd(&histm[wid * 257 + cb], cc);
        __syncthreads();
        unsigned int h = histm[tid] + histm[257 + tid] + histm[514 + tid] + histm[771 + tid];
        unsigned int s = h;
        for (int off = 1; off < 64; off <<= 1) {
            unsigned int o = __shfl_down(s, off);
            if (lane + off < 64) s += o;
        }
        if (lane == 0) histm[1028 + wid] = s;
        __syncthreads();
        unsigned int coarse = 0;
        for (int w = wid + 1; w < 4; ++w) coarse += histm[1028 + w];
        unsigned int incl = s + coarse, strict = incl - h;
        if (strict < kneed && kneed <= incl) { selb = (unsigned int)tid; selk = kneed - strict; }
        __syncthreads();
        prefix = (prefix << 8) | selb;
        kneed = selk;
        __syncthreads();
    }
    const unsigned int KA = prefix;
    const unsigned int g = 2048u - kneed;

    unsigned int ec = 0, mb = 0;
    #pragma unroll
    for (int t = 0; t < 16; ++t) {
        unsigned int kx = skey[tid + (t << 8)];
        if (kx == KA) ++ec;
        else if (kx < KA && kx > mb) mb = kx;
    }
    for (int off = 1; off < 64; off <<= 1) {
        ec += __shfl_xor(ec, off);
        unsigned int o = __shfl_xor(mb, off);
        mb = (o > mb) ? o : mb;
    }
    __syncthreads();
    if (lane == 0) { histm[wid] = ec; histm[8 + wid] = mb; }
    __syncthreads();
    unsigned int E  = histm[0] + histm[1] + histm[2] + histm[3];
    unsigned int MB = max(max(histm[8], histm[9]), max(histm[10], histm[11]));
    unsigned int KB = (g + E >= 2049u) ? KA : MB;
    const float scale = 0.5f * (finv(KA) + finv(KB));

    double lsd = 0.0; float gs = 0.0f;
    #pragma unroll
    for (int t = 0; t < 16; ++t) {
        float sl = scale * synth_sim[tid + (t << 8)];
        if (sl > -0.05f) { gs += 1.0f; lsd += (double)softplusf(sl); }
    }
    for (int off = 1; off < 64; off <<= 1) {
        lsd += __shfl_xor(lsd, off);
        gs  += __shfl_xor(gs, off);
    }
    if (lane == 0) { rs[wid] = lsd; rg[wid] = gs; }
    __syncthreads();
    if (tid == 0) {
        double L = rs[0] + rs[1] + rs[2] + rs[3];
        float  G = rg[0] + rg[1] + rg[2] + rg[3];
        double base = base_acc[0] / ((double)B * (double)B);
        double synth = (G > 0.0f) ? (L / ((double)G + 1e-8)) : 0.0;
        out[0] = (float)(base + 0.5 * synth);
    }
}

extern "C" void kernel_launch(void* const* d_in, const int* in_sizes, int n_in,
                              void* d_out, int out_size, void* d_ws, size_t ws_size,
                              hipStream_t stream) {
    const float* logits = (const float*)d_in[0];
    const float* text   = (const float*)d_in[1];
    const float* image  = (const float*)d_in[2];
    const float* bias   = (const float*)d_in[3];

    char* ws = (char*)d_ws;
    double*       base_acc = (double*)(ws + 0);
    unsigned int* mcount   = (unsigned int*)(ws + 8);
    unsigned int* Mkey     = (unsigned int*)(ws + 12);
    unsigned int* flags    = (unsigned int*)(ws + 64);            // 16 KB
    float*        rowsum   = (float*)(ws + 64 + 16384);
    unsigned int* rowmaxk  = (unsigned int*)(rowsum + B);
    float*        v        = (float*)(rowmaxk + B);
    float*        sim      = v + B;
    float*        ratio    = sim + B;
    int*          top_idx  = (int*)(ratio + B);
    float*        top_z    = (float*)(top_idx + (size_t)B * TOPK);
    unsigned int* lij      = (unsigned int*)(top_z + (size_t)B * TOPK);
    float*        lval     = (float*)(lij + (size_t)B * TOPK);

    // zero: header (base_acc, mcount, Mkey) + flags
    hipMemsetAsync(ws, 0, 64 + 16384, stream);

    k1_row     <<<B / 4, 256, 0, stream>>>(logits, text, image, bias, rowsum, rowmaxk,
                                           top_idx, top_z, ratio, flags);
    k1_fallback<<<B, 256, 0, stream>>>(logits, bias, flags, top_idx, top_z);
    k2_reduce  <<<1, 256, 0, stream>>>(rowsum, rowmaxk, Mkey, base_acc);
    k3_build   <<<(B * TOPK) / 256, 256, 0, stream>>>(top_z, top_idx, Mkey, mcount,
                                                      lij, lval);
    k4_sinkhorn<<<1, 128, 0, stream>>>(mcount, lij, lval, v);
    k5_synth   <<<B, 256, 0, stream>>>(top_idx, top_z, Mkey, v, image, text, sim);
    k78_final  <<<1, 256, 0, stream>>>(ratio, sim, base_acc, (float*)d_out);
}